// Round 5
// baseline (845.482 us; speedup 1.0000x reference)
//
#include <hip/hip_runtime.h>

#define EPSV 1e-8f
#define BN_EPS 1e-5f
#define LN_2PI 1.8378770664093453f

__device__ __forceinline__ float sigmoidf_(float x) { return 1.0f / (1.0f + expf(-x)); }

// ---------------- generic 3x3 pad1 conv on 8x8, split-K over ic chunks ----------------
__global__ __launch_bounds__(256) void k_conv3(
    const float* __restrict__ x, const float* __restrict__ w,
    const float* __restrict__ g, const float* __restrict__ b_,
    const float* __restrict__ m, const float* __restrict__ v,
    float* __restrict__ out, int OC, int nOcg, int nIcq, int icChunk)
{
    __shared__ float xs[6400];
    const int t = threadIdx.x;
    const int per_b = nOcg * nIcq;
    const int bidx = blockIdx.x / per_b;
    const int rem = blockIdx.x - bidx * per_b;
    const int ocg = rem / nIcq;
    const int icq = rem - ocg * nIcq;
    const int pix = t & 63, py = pix >> 3, px = pix & 7;
    const int ocb = t >> 6;
    const int ic0 = icq * icChunk;

    const int cells = icChunk * 100;
    for (int idx = t; idx < cells; idx += 256) {
        int icl = idx / 100;
        int c = idx - icl * 100;
        int iy = c / 10, ix = c - iy * 10;
        float val = 0.f;
        if (iy >= 1 && iy <= 8 && ix >= 1 && ix <= 8)
            val = x[(bidx * 256 + ic0 + icl) * 64 + (iy - 1) * 8 + (ix - 1)];
        xs[idx] = val;
    }
    __syncthreads();

    float acc[4] = {0.f, 0.f, 0.f, 0.f};
    for (int icl = 0; icl < icChunk; ++icl) {
        const float* wp = &w[((ocg * 16 + ocb) * 256 + ic0 + icl) * 9];
        const float* xr = &xs[icl * 100 + py * 10 + px];
        #pragma unroll
        for (int ky = 0; ky < 3; ++ky)
            #pragma unroll
            for (int kx = 0; kx < 3; ++kx) {
                float xv = xr[ky * 10 + kx];
                #pragma unroll
                for (int q = 0; q < 4; ++q)
                    acc[q] = fmaf(wp[q * 9216 + ky * 3 + kx], xv, acc[q]);
            }
    }
    #pragma unroll
    for (int q = 0; q < 4; ++q) {
        int oc = ocg * 16 + ocb + 4 * q;
        float sc = g[oc] * rsqrtf(v[oc] + BN_EPS);
        float add = acc[q] * sc;
        if (icq == 0) add += b_[oc] - m[oc] * sc;
        atomicAdd(&out[(bidx * OC + oc) * 64 + pix], add);
    }
}

__global__ void k_sig(float* __restrict__ a, int n)
{
    int i = blockIdx.x * 256 + threadIdx.x;
    if (i < n) a[i] = 1.f / (1.f + expf(-a[i]));
}

// ---------------- EM routing, conv-type (k=3, pad=1), A=B=16, P=16 ----------------
// grid: 32*64 blocks (b,l); block 768 = (kg in 48) x (o in 16); thread owns k = kg+48s, s=0..2.
// Wave = 4 kg x 16 o  ->  softmax over o is a width-16 shfl butterfly (pure registers);
// moment reduction = 3-term serial + shfl xor 16/32 (kg-in-wave) + LDS stage-2 over 12 waves.
// Routing logits never touch LDS. sig fused: sig = E2 - mu^2*(2-beta), beta = rs/(rs+eps).
__global__ __launch_bounds__(768, 2) void k_em_conv(
    const float* __restrict__ a_in, const float* __restrict__ pose_in,
    const float* __restrict__ W, const float* __restrict__ bu, const float* __restrict__ ba,
    const float* __restrict__ bng, const float* __restrict__ bnb,
    const float* __restrict__ bnm, const float* __restrict__ bnv,
    float* __restrict__ a_out_g, float* __restrict__ pose_out)
{
    __shared__ float red_pm[3264] __attribute__((aligned(16)));  // [(w*16+o)*17+p]; aliased pc stage [k*20+p]
    __shared__ float red_pq[3264];
    __shared__ float prsum[192];      // [w*16+o]
    __shared__ float a_s[160];
    __shared__ float mu_s[272], lsig_s[272], isig_s[272];  // [o*17+p]
    __shared__ float aout_s[16], laout_s[16];

    const int t = threadIdx.x;
    const int bidx = blockIdx.x >> 6;
    const int l = blockIdx.x & 63;
    const int y = l >> 3, xo = l & 7;
    const int kg = t >> 4;            // 0..47
    const int o = t & 15;
    const int w_id = t >> 6;          // 0..11
    const int lane = t & 63;

    float* pc_s = red_pm;

    // ---- stage pose patches + a patches ----
    for (int idx = t; idx < 2304; idx += 768) {
        int k = idx >> 4, p = idx & 15;
        int a = k & 15, kk = k >> 4;
        int iy = y + kk / 3 - 1, ix = xo + (kk % 3) - 1;
        float val = 0.f;
        if (iy >= 0 && iy < 8 && ix >= 0 && ix < 8)
            val = pose_in[(bidx * 256 + a * 16 + p) * 64 + iy * 8 + ix];
        pc_s[k * 20 + p] = val;
    }
    if (t < 144) {
        int a = t & 15, kk = t >> 4;
        int iy = y + kk / 3 - 1, ix = xo + (kk % 3) - 1;
        a_s[t] = (iy >= 0 && iy < 8 && ix >= 0 && ix < 8) ? a_in[(bidx * 16 + a) * 64 + iy * 8 + ix] : 0.f;
    }
    __syncthreads();

    // ---- votes: 3 per thread, k = kg + 48*s ----
    float v[3][16];
    const float4* W4 = reinterpret_cast<const float4*>(W);
    #pragma unroll
    for (int s = 0; s < 3; ++s) {
        int k = kg + 48 * s;
        float pcl[16];
        #pragma unroll
        for (int c = 0; c < 4; ++c) {
            float4 p4 = *reinterpret_cast<const float4*>(&pc_s[k * 20 + c * 4]);
            pcl[c * 4 + 0] = p4.x; pcl[c * 4 + 1] = p4.y; pcl[c * 4 + 2] = p4.z; pcl[c * 4 + 3] = p4.w;
        }
        float wk[16];
        #pragma unroll
        for (int c = 0; c < 4; ++c) {
            float4 w4 = W4[(k * 16 + o) * 4 + c];
            wk[c * 4 + 0] = w4.x; wk[c * 4 + 1] = w4.y; wk[c * 4 + 2] = w4.z; wk[c * 4 + 3] = w4.w;
        }
        #pragma unroll
        for (int i = 0; i < 4; ++i)
            #pragma unroll
            for (int j = 0; j < 4; ++j) {
                float sum = 0.f;
                #pragma unroll
                for (int h = 0; h < 4; ++h) sum = fmaf(pcl[i * 4 + h], wk[h * 4 + j], sum);
                v[s][i * 4 + j] = sum;
            }
    }
    float av[3];
    #pragma unroll
    for (int s = 0; s < 3; ++s) av[s] = a_s[kg + 48 * s];
    __syncthreads();  // pc_s reads done; red region reused below

    float lg[3] = {0.f, 0.f, 0.f};   // routing logits (softmax(0) = uniform 1/16)
    for (int it = 0; it < 3; ++it) {
        float lam = (it == 0) ? 5.0e-4f : ((it == 1) ? 9.75e-4f : 1.42625e-3f);
        // ---- softmax over o (in-wave, width 16) + a-weight + renorm over o ----
        float rw[3];
        #pragma unroll
        for (int s = 0; s < 3; ++s) {
            float mx = lg[s];
            #pragma unroll
            for (int mk = 1; mk <= 8; mk <<= 1) mx = fmaxf(mx, __shfl_xor(mx, mk, 16));
            float e = expf(lg[s] - mx);
            float den = e;
            #pragma unroll
            for (int mk = 1; mk <= 8; mk <<= 1) den += __shfl_xor(den, mk, 16);
            float rr = (e / den) * av[s];
            float den2 = rr;
            #pragma unroll
            for (int mk = 1; mk <= 8; mk <<= 1) den2 += __shfl_xor(den2, mk, 16);
            rw[s] = rr / (den2 + EPSV);
        }
        // ---- moments: serial over s, shfl over kg-in-wave, LDS stage-2 ----
        float prw = rw[0] + rw[1] + rw[2];
        float pm[16], pq[16];
        #pragma unroll
        for (int p = 0; p < 16; ++p) { pm[p] = 0.f; pq[p] = 0.f; }
        #pragma unroll
        for (int s = 0; s < 3; ++s) {
            float r = rw[s];
            #pragma unroll
            for (int p = 0; p < 16; ++p) {
                float vv = v[s][p];
                pm[p] = fmaf(r, vv, pm[p]);
                pq[p] = fmaf(r * vv, vv, pq[p]);
            }
        }
        prw += __shfl_xor(prw, 16, 64); prw += __shfl_xor(prw, 32, 64);
        #pragma unroll
        for (int p = 0; p < 16; ++p) {
            pm[p] += __shfl_xor(pm[p], 16, 64); pm[p] += __shfl_xor(pm[p], 32, 64);
            pq[p] += __shfl_xor(pq[p], 16, 64); pq[p] += __shfl_xor(pq[p], 32, 64);
        }
        if (lane < 16) {
            prsum[w_id * 16 + o] = prw;
            int row = (w_id * 16 + o) * 17;
            #pragma unroll
            for (int p = 0; p < 16; ++p) { red_pm[row + p] = pm[p]; red_pq[row + p] = pq[p]; }
        }
        __syncthreads();
        // ---- stage-2: 12 partials -> mu, sig, cost, a_out (fused) ----
        if (t < 256) {
            int oo = t >> 4, p = t & 15;
            float spm = 0.f, spq = 0.f, srs = 0.f;
            #pragma unroll
            for (int u = 0; u < 12; ++u) {
                int row = (u * 16 + oo) * 17;
                spm += red_pm[row + p];
                spq += red_pq[row + p];
                srs += prsum[u * 16 + oo];
            }
            float invr = 1.f / (srs + EPSV);
            float mu = spm * invr;
            float beta = srs * invr;
            float E2 = spq * invr;
            float sig = fmaf(-(2.f - beta) * mu, mu, E2) + EPSV;
            float ls = logf(sig);
            mu_s[oo * 17 + p] = mu;
            lsig_s[oo * 17 + p] = ls;
            isig_s[oo * 17 + p] = 1.f / sig;
            float cost = (bu[oo] + 0.5f * ls) * srs;
            #pragma unroll
            for (int mk = 1; mk <= 8; mk <<= 1) cost += __shfl_xor(cost, mk, 16);
            if (p == 0) {
                float ao = sigmoidf_(lam * (ba[oo] - cost));
                aout_s[oo] = ao; laout_s[oo] = logf(ao);
            }
        }
        __syncthreads();
        // ---- E-step: logits in registers ----
        if (it < 2) {
            float s0 = 0.f, s1 = 0.f, s2 = 0.f;
            float cst = -8.f * LN_2PI;
            const float la = laout_s[o];
            #pragma unroll
            for (int p = 0; p < 16; ++p) {
                float ml = mu_s[o * 17 + p];
                float isg = isig_s[o * 17 + p];
                cst -= 0.5f * lsig_s[o * 17 + p];
                float d0 = v[0][p] - ml; s0 = fmaf(d0 * d0, isg, s0);
                float d1 = v[1][p] - ml; s1 = fmaf(d1 * d1, isg, s1);
                float d2 = v[2][p] - ml; s2 = fmaf(d2 * d2, isg, s2);
            }
            lg[0] = fmaf(-0.5f, s0, cst) + la;
            lg[1] = fmaf(-0.5f, s1, cst) + la;
            lg[2] = fmaf(-0.5f, s2, cst) + la;
        }
    }
    // ---- outputs: BN(pose=mu) and a_out ----
    if (t < 256) {
        float sc = bng[t] * rsqrtf(bnv[t] + BN_EPS);
        float mu = mu_s[(t >> 4) * 17 + (t & 15)];
        pose_out[(bidx * 256 + t) * 64 + l] = (mu - bnm[t]) * sc + bnb[t];
    }
    if (t < 16) a_out_g[(bidx * 16 + t) * 64 + l] = aout_s[t];
}

// ---------------- EM routing, FC-type (k=4, pad=0), A=16, B=10, P=16 ----------------
__global__ __launch_bounds__(320, 2) void k_em_fc(
    const float* __restrict__ a_in, const float* __restrict__ pose_in,
    const float* __restrict__ W, const float* __restrict__ bu, const float* __restrict__ ba,
    float* __restrict__ out)
{
    __shared__ float pcs[5440];
    __shared__ float rws[256 * 11];
    __shared__ float ain_s[256];
    __shared__ float mu_s[160];
    __shared__ float lsig_s[160];
    __shared__ float isig_s[160];
    __shared__ float cbuf[160];
    __shared__ float rs_s[10], aout_s[10], laout_s[10];
    __shared__ float bu_s[10], ba_s[10];

    const int t = threadIdx.x;
    const int bidx = blockIdx.x / 25;
    const int l = blockIdx.x % 25;
    const int y = l / 5, xo = l % 5;
    const int o = t >> 5, g = t & 31;

    for (int idx = t; idx < 4096; idx += 320) {
        int k = idx >> 4, p = idx & 15;
        int a = k & 15, kk = k >> 4;
        int iy = y + (kk >> 2), ix = xo + (kk & 3);
        pcs[k * 17 + p] = pose_in[((bidx * 256 + a * 16 + p) << 6) + iy * 8 + ix];
    }
    if (t < 256) {
        int a = t & 15, kk = t >> 4;
        int iy = y + (kk >> 2), ix = xo + (kk & 3);
        ain_s[t] = a_in[((bidx * 16 + a) << 6) + iy * 8 + ix];
    }
    if (t < 10) { bu_s[t] = bu[t]; ba_s[t] = ba[t]; }
    __syncthreads();

    float v[8][16];
    const float4* W4 = reinterpret_cast<const float4*>(W);
    #pragma unroll
    for (int jj = 0; jj < 8; ++jj) {
        int k = jj * 32 + g;
        float pcl[16];
        #pragma unroll
        for (int p = 0; p < 16; ++p) pcl[p] = pcs[k * 17 + p];
        float wk[16];
        #pragma unroll
        for (int c = 0; c < 4; ++c) {
            float4 w4 = W4[(k * 10 + o) * 4 + c];
            wk[c * 4 + 0] = w4.x; wk[c * 4 + 1] = w4.y; wk[c * 4 + 2] = w4.z; wk[c * 4 + 3] = w4.w;
        }
        #pragma unroll
        for (int i = 0; i < 4; ++i)
            #pragma unroll
            for (int j = 0; j < 4; ++j) {
                float s = 0.f;
                #pragma unroll
                for (int h = 0; h < 4; ++h) s = fmaf(pcl[i * 4 + h], wk[h * 4 + j], s);
                v[jj][i * 4 + j] = s;
            }
    }
    float* red = pcs;

    float ml[16];
    for (int it = 0; it < 3; ++it) {
        float lam = (it == 0) ? 5.0e-4f : ((it == 1) ? 9.75e-4f : 1.42625e-3f);
        __syncthreads();
        if (t < 256) {
            float rr[10];
            if (it > 0) {
                float mx = -1e30f;
                #pragma unroll
                for (int oo = 0; oo < 10; ++oo) { rr[oo] = rws[t * 11 + oo]; mx = fmaxf(mx, rr[oo]); }
                float den = 0.f;
                #pragma unroll
                for (int oo = 0; oo < 10; ++oo) { float e = expf(rr[oo] - mx); rr[oo] = e; den += e; }
                float inv = 1.f / den;
                #pragma unroll
                for (int oo = 0; oo < 10; ++oo) rr[oo] *= inv;
            } else {
                #pragma unroll
                for (int oo = 0; oo < 10; ++oo) rr[oo] = 0.1f;
            }
            float av = ain_s[t];
            float den = EPSV;
            #pragma unroll
            for (int oo = 0; oo < 10; ++oo) { rr[oo] *= av; den += rr[oo]; }
            float inv = 1.f / den;
            #pragma unroll
            for (int oo = 0; oo < 10; ++oo) rws[t * 11 + oo] = rr[oo] * inv;
        }
        __syncthreads();
        float rwl[8]; float prs = 0.f;
        #pragma unroll
        for (int jj = 0; jj < 8; ++jj) { rwl[jj] = rws[(jj * 32 + g) * 11 + o]; prs += rwl[jj]; }
        #pragma unroll
        for (int off = 16; off > 0; off >>= 1) prs += __shfl_xor(prs, off, 32);
        if (g == 0) rs_s[o] = prs;
        __syncthreads();
        {
            float pm[16];
            #pragma unroll
            for (int p = 0; p < 16; ++p) pm[p] = 0.f;
            #pragma unroll
            for (int jj = 0; jj < 8; ++jj)
                #pragma unroll
                for (int p = 0; p < 16; ++p) pm[p] = fmaf(rwl[jj], v[jj][p], pm[p]);
            #pragma unroll
            for (int p = 0; p < 16; ++p) red[t * 17 + p] = pm[p];
        }
        __syncthreads();
        if (t < 160) {
            int oo = t >> 4, p = t & 15; float s = 0.f;
            #pragma unroll
            for (int gg = 0; gg < 32; ++gg) s += red[(oo * 32 + gg) * 17 + p];
            mu_s[t] = s / (rs_s[oo] + EPSV);
        }
        __syncthreads();
        #pragma unroll
        for (int p = 0; p < 16; ++p) ml[p] = mu_s[o * 16 + p];
        {
            float pq[16];
            #pragma unroll
            for (int p = 0; p < 16; ++p) pq[p] = 0.f;
            #pragma unroll
            for (int jj = 0; jj < 8; ++jj)
                #pragma unroll
                for (int p = 0; p < 16; ++p) { float d = v[jj][p] - ml[p]; pq[p] = fmaf(rwl[jj] * d, d, pq[p]); }
            #pragma unroll
            for (int p = 0; p < 16; ++p) red[t * 17 + p] = pq[p];
        }
        __syncthreads();
        if (t < 160) {
            int oo = t >> 4, p = t & 15; float s = 0.f;
            #pragma unroll
            for (int gg = 0; gg < 32; ++gg) s += red[(oo * 32 + gg) * 17 + p];
            s = s / (rs_s[oo] + EPSV) + EPSV;
            float ls = logf(s);
            lsig_s[t] = ls; isig_s[t] = 1.f / s;
            cbuf[t] = (bu_s[oo] + 0.5f * ls) * rs_s[oo];
        }
        __syncthreads();
        if (t < 10) {
            float c = 0.f;
            #pragma unroll
            for (int p = 0; p < 16; ++p) c += cbuf[t * 16 + p];
            float ao = sigmoidf_(lam * (ba_s[t] - c));
            aout_s[t] = ao; laout_s[t] = logf(ao);
        }
        __syncthreads();
        if (it < 2) {
            float isl[16]; float cst = -8.f * LN_2PI;
            #pragma unroll
            for (int p = 0; p < 16; ++p) { isl[p] = isig_s[o * 16 + p]; cst -= 0.5f * lsig_s[o * 16 + p]; }
            const float la = laout_s[o];
            #pragma unroll
            for (int jj = 0; jj < 8; ++jj) {
                float s = 0.f;
                #pragma unroll
                for (int p = 0; p < 16; ++p) { float d = v[jj][p] - ml[p]; s = fmaf(d * d, isl[p], s); }
                rws[(jj * 32 + g) * 11 + o] = -0.5f * s + cst + la;
            }
        }
    }
    if (t < 10) atomicAdd(&out[bidx * 10 + t], aout_s[t] * 0.04f);
}

extern "C" void kernel_launch(void* const* d_in, const int* in_sizes, int n_in,
                              void* d_out, int out_size, void* d_ws, size_t ws_size,
                              hipStream_t stream)
{
    const float* x           = (const float*)d_in[0];
    const float* conv_a_w    = (const float*)d_in[1];
    const float* conv_pose_w = (const float*)d_in[2];
    const float* bn_a_g = (const float*)d_in[3];
    const float* bn_a_b = (const float*)d_in[4];
    const float* bn_a_m = (const float*)d_in[5];
    const float* bn_a_v = (const float*)d_in[6];
    const float* bn_p_g = (const float*)d_in[7];
    const float* bn_p_b = (const float*)d_in[8];
    const float* bn_p_m = (const float*)d_in[9];
    const float* bn_p_v = (const float*)d_in[10];
    const float* em0_W  = (const float*)d_in[11];
    const float* em0_bu = (const float*)d_in[12];
    const float* em0_ba = (const float*)d_in[13];
    const float* bn0_g  = (const float*)d_in[14];
    const float* bn0_b  = (const float*)d_in[15];
    const float* bn0_m  = (const float*)d_in[16];
    const float* bn0_v  = (const float*)d_in[17];
    const float* em1_W  = (const float*)d_in[18];
    const float* em1_bu = (const float*)d_in[19];
    const float* em1_ba = (const float*)d_in[20];
    const float* bn1_g  = (const float*)d_in[21];
    const float* bn1_b  = (const float*)d_in[22];
    const float* bn1_m  = (const float*)d_in[23];
    const float* bn1_v  = (const float*)d_in[24];
    const float* fc_W   = (const float*)d_in[25];
    const float* fc_bu  = (const float*)d_in[26];
    const float* fc_ba  = (const float*)d_in[27];

    float* ws    = (float*)d_ws;
    float* a0    = ws;
    float* pose0 = a0 + 32768;
    float* a1    = pose0 + 524288;
    float* pose1 = a1 + 32768;
    float* a2    = pose1 + 524288;
    float* pose2 = a2 + 32768;
    float* out   = (float*)d_out;

    hipMemsetAsync(d_out, 0, (size_t)out_size * sizeof(float), stream);
    hipMemsetAsync(a0, 0, (size_t)(32768 + 524288) * sizeof(float), stream);
    k_conv3<<<256, 256, 0, stream>>>(x, conv_a_w, bn_a_g, bn_a_b, bn_a_m, bn_a_v,
                                     a0, 16, 1, 8, 32);
    k_conv3<<<2048, 256, 0, stream>>>(x, conv_pose_w, bn_p_g, bn_p_b, bn_p_m, bn_p_v,
                                      pose0, 256, 16, 4, 64);
    k_sig<<<128, 256, 0, stream>>>(a0, 32768);
    k_em_conv<<<2048, 768, 0, stream>>>(a0, pose0, em0_W, em0_bu, em0_ba,
                                        bn0_g, bn0_b, bn0_m, bn0_v, a1, pose1);
    k_em_conv<<<2048, 768, 0, stream>>>(a1, pose1, em1_W, em1_bu, em1_ba,
                                        bn1_g, bn1_b, bn1_m, bn1_v, a2, pose2);
    k_em_fc<<<800, 320, 0, stream>>>(a2, pose2, fc_W, fc_bu, fc_ba, out);
}

// Round 6
// 695.928 us; speedup vs baseline: 1.2149x; 1.2149x over previous
//
#include <hip/hip_runtime.h>

#define EPSV 1e-8f
#define BN_EPS 1e-5f
#define LN_2PI 1.8378770664093453f

__device__ __forceinline__ float sigmoidf_(float x) { return 1.0f / (1.0f + expf(-x)); }

// ---------------- generic 3x3 pad1 conv on 8x8, split-K over ic chunks ----------------
__global__ __launch_bounds__(256) void k_conv3(
    const float* __restrict__ x, const float* __restrict__ w,
    const float* __restrict__ g, const float* __restrict__ b_,
    const float* __restrict__ m, const float* __restrict__ v,
    float* __restrict__ out, int OC, int nOcg, int nIcq, int icChunk)
{
    __shared__ float xs[6400];
    const int t = threadIdx.x;
    const int per_b = nOcg * nIcq;
    const int bidx = blockIdx.x / per_b;
    const int rem = blockIdx.x - bidx * per_b;
    const int ocg = rem / nIcq;
    const int icq = rem - ocg * nIcq;
    const int pix = t & 63, py = pix >> 3, px = pix & 7;
    const int ocb = t >> 6;
    const int ic0 = icq * icChunk;

    const int cells = icChunk * 100;
    for (int idx = t; idx < cells; idx += 256) {
        int icl = idx / 100;
        int c = idx - icl * 100;
        int iy = c / 10, ix = c - iy * 10;
        float val = 0.f;
        if (iy >= 1 && iy <= 8 && ix >= 1 && ix <= 8)
            val = x[(bidx * 256 + ic0 + icl) * 64 + (iy - 1) * 8 + (ix - 1)];
        xs[idx] = val;
    }
    __syncthreads();

    float acc[4] = {0.f, 0.f, 0.f, 0.f};
    for (int icl = 0; icl < icChunk; ++icl) {
        const float* wp = &w[((ocg * 16 + ocb) * 256 + ic0 + icl) * 9];
        const float* xr = &xs[icl * 100 + py * 10 + px];
        #pragma unroll
        for (int ky = 0; ky < 3; ++ky)
            #pragma unroll
            for (int kx = 0; kx < 3; ++kx) {
                float xv = xr[ky * 10 + kx];
                #pragma unroll
                for (int q = 0; q < 4; ++q)
                    acc[q] = fmaf(wp[q * 9216 + ky * 3 + kx], xv, acc[q]);
            }
    }
    #pragma unroll
    for (int q = 0; q < 4; ++q) {
        int oc = ocg * 16 + ocb + 4 * q;
        float sc = g[oc] * rsqrtf(v[oc] + BN_EPS);
        float add = acc[q] * sc;
        if (icq == 0) add += b_[oc] - m[oc] * sc;
        atomicAdd(&out[(bidx * OC + oc) * 64 + pix], add);
    }
}

__global__ void k_sig(float* __restrict__ a, int n)
{
    int i = blockIdx.x * 256 + threadIdx.x;
    if (i < n) a[i] = 1.f / (1.f + expf(-a[i]));
}

// ---------------- EM routing, conv-type (k=3, pad=1), A=B=16, P=16 ----------------
// grid: 32*64 blocks (b,l); block 768 = (kg in 48) x (o in 16); thread owns k = kg+48s, s=0..2.
// Wave = 4 kg x 16 o. Softmax over o: width-16 shfl. Moments: per-p scalar partials (no
// pm[16]/pq[16] arrays -> no spill), shfl over kg-in-wave, LDS stage-2 over 12 waves.
__global__ __launch_bounds__(768) void k_em_conv(
    const float* __restrict__ a_in, const float* __restrict__ pose_in,
    const float* __restrict__ W, const float* __restrict__ bu, const float* __restrict__ ba,
    const float* __restrict__ bng, const float* __restrict__ bnb,
    const float* __restrict__ bnm, const float* __restrict__ bnv,
    float* __restrict__ a_out_g, float* __restrict__ pose_out)
{
    __shared__ float red_pm[3264] __attribute__((aligned(16)));  // aliased pc stage [k*20+p]
    __shared__ float red_pq[3264];
    __shared__ float prsum[192];
    __shared__ float a_s[160];
    __shared__ float mu_s[272], lsig_s[272], isig_s[272];  // [o*17+p]
    __shared__ float aout_s[16], laout_s[16];

    const int t = threadIdx.x;
    const int bidx = blockIdx.x >> 6;
    const int l = blockIdx.x & 63;
    const int y = l >> 3, xo = l & 7;
    const int kg = t >> 4;            // 0..47
    const int o = t & 15;
    const int w_id = t >> 6;          // 0..11
    const int lane = t & 63;

    float* pc_s = red_pm;

    for (int idx = t; idx < 2304; idx += 768) {
        int k = idx >> 4, p = idx & 15;
        int a = k & 15, kk = k >> 4;
        int iy = y + kk / 3 - 1, ix = xo + (kk % 3) - 1;
        float val = 0.f;
        if (iy >= 0 && iy < 8 && ix >= 0 && ix < 8)
            val = pose_in[(bidx * 256 + a * 16 + p) * 64 + iy * 8 + ix];
        pc_s[k * 20 + p] = val;
    }
    if (t < 144) {
        int a = t & 15, kk = t >> 4;
        int iy = y + kk / 3 - 1, ix = xo + (kk % 3) - 1;
        a_s[t] = (iy >= 0 && iy < 8 && ix >= 0 && ix < 8) ? a_in[(bidx * 16 + a) * 64 + iy * 8 + ix] : 0.f;
    }
    __syncthreads();

    // ---- votes: stream over h so only pcl[16] + one W row live ----
    float v[3][16];
    const float4* W4 = reinterpret_cast<const float4*>(W);
    #pragma unroll
    for (int s = 0; s < 3; ++s) {
        int k = kg + 48 * s;
        float pcl[16];
        #pragma unroll
        for (int c = 0; c < 4; ++c) {
            float4 p4 = *reinterpret_cast<const float4*>(&pc_s[k * 20 + c * 4]);
            pcl[c * 4 + 0] = p4.x; pcl[c * 4 + 1] = p4.y; pcl[c * 4 + 2] = p4.z; pcl[c * 4 + 3] = p4.w;
        }
        #pragma unroll
        for (int p = 0; p < 16; ++p) v[s][p] = 0.f;
        #pragma unroll
        for (int h = 0; h < 4; ++h) {
            float4 wr = W4[(k * 16 + o) * 4 + h];
            #pragma unroll
            for (int i = 0; i < 4; ++i) {
                float a = pcl[i * 4 + h];
                v[s][i * 4 + 0] = fmaf(a, wr.x, v[s][i * 4 + 0]);
                v[s][i * 4 + 1] = fmaf(a, wr.y, v[s][i * 4 + 1]);
                v[s][i * 4 + 2] = fmaf(a, wr.z, v[s][i * 4 + 2]);
                v[s][i * 4 + 3] = fmaf(a, wr.w, v[s][i * 4 + 3]);
            }
        }
    }
    float av[3];
    #pragma unroll
    for (int s = 0; s < 3; ++s) av[s] = a_s[kg + 48 * s];
    __syncthreads();  // pc_s dead; red region reused

    float lg[3] = {0.f, 0.f, 0.f};
    for (int it = 0; it < 3; ++it) {
        float lam = (it == 0) ? 5.0e-4f : ((it == 1) ? 9.75e-4f : 1.42625e-3f);
        // ---- softmax over o (in-wave) + a-weight + renorm ----
        float rw[3];
        #pragma unroll
        for (int s = 0; s < 3; ++s) {
            float mx = lg[s];
            #pragma unroll
            for (int mk = 1; mk <= 8; mk <<= 1) mx = fmaxf(mx, __shfl_xor(mx, mk, 16));
            float e = expf(lg[s] - mx);
            float den = e;
            #pragma unroll
            for (int mk = 1; mk <= 8; mk <<= 1) den += __shfl_xor(den, mk, 16);
            float rr = (e / den) * av[s];
            float den2 = rr;
            #pragma unroll
            for (int mk = 1; mk <= 8; mk <<= 1) den2 += __shfl_xor(den2, mk, 16);
            rw[s] = rr / (den2 + EPSV);
        }
        // ---- moments: per-p scalars, shfl over kg-in-wave, store partials ----
        float prw = rw[0] + rw[1] + rw[2];
        prw += __shfl_xor(prw, 16, 64); prw += __shfl_xor(prw, 32, 64);
        const int row = (w_id * 16 + o) * 17;
        if (lane < 16) prsum[w_id * 16 + o] = prw;
        #pragma unroll
        for (int p = 0; p < 16; ++p) {
            float v0 = v[0][p], v1 = v[1][p], v2 = v[2][p];
            float pmp = rw[0] * v0; pmp = fmaf(rw[1], v1, pmp); pmp = fmaf(rw[2], v2, pmp);
            float pqp = rw[0] * v0 * v0; pqp = fmaf(rw[1] * v1, v1, pqp); pqp = fmaf(rw[2] * v2, v2, pqp);
            pmp += __shfl_xor(pmp, 16, 64); pmp += __shfl_xor(pmp, 32, 64);
            pqp += __shfl_xor(pqp, 16, 64); pqp += __shfl_xor(pqp, 32, 64);
            if (lane < 16) { red_pm[row + p] = pmp; red_pq[row + p] = pqp; }
        }
        __syncthreads();
        // ---- stage-2: 12 partials -> mu, sig, cost, a_out ----
        if (t < 256) {
            int oo = t >> 4, p = t & 15;
            float spm = 0.f, spq = 0.f, srs = 0.f;
            #pragma unroll
            for (int u = 0; u < 12; ++u) {
                int r2 = (u * 16 + oo) * 17;
                spm += red_pm[r2 + p];
                spq += red_pq[r2 + p];
                srs += prsum[u * 16 + oo];
            }
            float invr = 1.f / (srs + EPSV);
            float mu = spm * invr;
            float beta = srs * invr;
            float E2 = spq * invr;
            float sig = fmaf(-(2.f - beta) * mu, mu, E2) + EPSV;
            float ls = logf(sig);
            mu_s[oo * 17 + p] = mu;
            lsig_s[oo * 17 + p] = ls;
            isig_s[oo * 17 + p] = 1.f / sig;
            float cost = (bu[oo] + 0.5f * ls) * srs;
            #pragma unroll
            for (int mk = 1; mk <= 8; mk <<= 1) cost += __shfl_xor(cost, mk, 16);
            if (p == 0) {
                float ao = sigmoidf_(lam * (ba[oo] - cost));
                aout_s[oo] = ao; laout_s[oo] = logf(ao);
            }
        }
        __syncthreads();
        // ---- E-step ----
        if (it < 2) {
            float s0 = 0.f, s1 = 0.f, s2 = 0.f;
            float cst = -8.f * LN_2PI;
            const float la = laout_s[o];
            #pragma unroll
            for (int p = 0; p < 16; ++p) {
                float ml = mu_s[o * 17 + p];
                float isg = isig_s[o * 17 + p];
                cst -= 0.5f * lsig_s[o * 17 + p];
                float d0 = v[0][p] - ml; s0 = fmaf(d0 * d0, isg, s0);
                float d1 = v[1][p] - ml; s1 = fmaf(d1 * d1, isg, s1);
                float d2 = v[2][p] - ml; s2 = fmaf(d2 * d2, isg, s2);
            }
            lg[0] = fmaf(-0.5f, s0, cst) + la;
            lg[1] = fmaf(-0.5f, s1, cst) + la;
            lg[2] = fmaf(-0.5f, s2, cst) + la;
        }
    }
    if (t < 256) {
        float sc = bng[t] * rsqrtf(bnv[t] + BN_EPS);
        float mu = mu_s[(t >> 4) * 17 + (t & 15)];
        pose_out[(bidx * 256 + t) * 64 + l] = (mu - bnm[t]) * sc + bnb[t];
    }
    if (t < 16) a_out_g[(bidx * 16 + t) * 64 + l] = aout_s[t];
}

// ---------------- EM routing, FC-type (k=4, pad=0), A=16, B=10, P=16 ----------------
// grid: 32*25 blocks; block 640 = (o in 10 waves) x (g in 64 lanes); thread owns
// k = g+64s, s=0..3 -> v[4][16]=64 regs (no spill). Moments: per-p partials into a
// skewed LDS matrix; stage-2 sums 64 rows. Softmax over o via rws[k][o] (cross-wave).
__global__ __launch_bounds__(640) void k_em_fc(
    const float* __restrict__ a_in, const float* __restrict__ pose_in,
    const float* __restrict__ W, const float* __restrict__ bu, const float* __restrict__ ba,
    float* __restrict__ out)
{
    __shared__ float red[10896] __attribute__((aligned(16)));  // pcs[k*20+p] (votes) / [t*17+(t>>6)+p] (iters)
    __shared__ float rws[2816];       // [k*11+o]
    __shared__ float ain_s[256];
    __shared__ float mu_s[176], lsig_s[176], isig_s[176];  // [o*17+p]
    __shared__ float rs_s[16], aout_s[16], laout_s[16];

    const int t = threadIdx.x;
    const int bidx = blockIdx.x / 25;
    const int l = blockIdx.x % 25;
    const int y = l / 5, xo = l % 5;
    const int o = t >> 6;             // 0..9
    const int g = t & 63;

    float* pcs = red;
    for (int idx = t; idx < 4096; idx += 640) {
        int k = idx >> 4, p = idx & 15;
        int a = k & 15, kk = k >> 4;
        int iy = y + (kk >> 2), ix = xo + (kk & 3);
        pcs[k * 20 + p] = pose_in[((bidx * 256 + a * 16 + p) << 6) + iy * 8 + ix];
    }
    if (t < 256) {
        int a = t & 15, kk = t >> 4;
        int iy = y + (kk >> 2), ix = xo + (kk & 3);
        ain_s[t] = a_in[((bidx * 16 + a) << 6) + iy * 8 + ix];
    }
    __syncthreads();

    // ---- votes: stream over h ----
    float v[4][16];
    const float4* W4 = reinterpret_cast<const float4*>(W);
    #pragma unroll
    for (int s = 0; s < 4; ++s) {
        int k = g + 64 * s;
        float pcl[16];
        #pragma unroll
        for (int c = 0; c < 4; ++c) {
            float4 p4 = *reinterpret_cast<const float4*>(&pcs[k * 20 + c * 4]);
            pcl[c * 4 + 0] = p4.x; pcl[c * 4 + 1] = p4.y; pcl[c * 4 + 2] = p4.z; pcl[c * 4 + 3] = p4.w;
        }
        #pragma unroll
        for (int p = 0; p < 16; ++p) v[s][p] = 0.f;
        #pragma unroll
        for (int h = 0; h < 4; ++h) {
            float4 wr = W4[(k * 10 + o) * 4 + h];
            #pragma unroll
            for (int i = 0; i < 4; ++i) {
                float a = pcl[i * 4 + h];
                v[s][i * 4 + 0] = fmaf(a, wr.x, v[s][i * 4 + 0]);
                v[s][i * 4 + 1] = fmaf(a, wr.y, v[s][i * 4 + 1]);
                v[s][i * 4 + 2] = fmaf(a, wr.z, v[s][i * 4 + 2]);
                v[s][i * 4 + 3] = fmaf(a, wr.w, v[s][i * 4 + 3]);
            }
        }
    }
    float av4[4];
    #pragma unroll
    for (int s = 0; s < 4; ++s) av4[s] = ain_s[g + 64 * s];
    __syncthreads();  // pcs dead; red reused

    const int rowb = t * 17 + o;      // skewed row base
    for (int it = 0; it < 3; ++it) {
        float lam = (it == 0) ? 5.0e-4f : ((it == 1) ? 9.75e-4f : 1.42625e-3f);
        // ---- per-k softmax over o + a-weight + renorm (array-free; sum_o softmax = 1 -> den2 = av) ----
        if (t < 256) {
            float av = ain_s[t];
            if (it == 0) {
                float val = 0.1f * av / (av + EPSV);
                #pragma unroll
                for (int oo = 0; oo < 10; ++oo) rws[t * 11 + oo] = val;
            } else {
                float mx = -1e30f;
                #pragma unroll
                for (int oo = 0; oo < 10; ++oo) mx = fmaxf(mx, rws[t * 11 + oo]);
                float den = 0.f;
                #pragma unroll
                for (int oo = 0; oo < 10; ++oo) den += expf(rws[t * 11 + oo] - mx);
                float sc = av / (den * (av + EPSV));
                #pragma unroll
                for (int oo = 0; oo < 10; ++oo) rws[t * 11 + oo] = expf(rws[t * 11 + oo] - mx) * sc;
            }
        }
        __syncthreads();
        // ---- rsum over k: 4-term serial + width-64 shfl ----
        float rwl[4]; float prs = 0.f;
        #pragma unroll
        for (int s = 0; s < 4; ++s) { rwl[s] = rws[(g + 64 * s) * 11 + o]; prs += rwl[s]; }
        #pragma unroll
        for (int off = 32; off > 0; off >>= 1) prs += __shfl_xor(prs, off, 64);
        if (g == 0) rs_s[o] = prs;
        // ---- pm partials ----
        #pragma unroll
        for (int p = 0; p < 16; ++p) {
            float pmp = rwl[0] * v[0][p];
            pmp = fmaf(rwl[1], v[1][p], pmp);
            pmp = fmaf(rwl[2], v[2][p], pmp);
            pmp = fmaf(rwl[3], v[3][p], pmp);
            red[rowb + p] = pmp;
        }
        __syncthreads();
        if (t < 160) {
            int oo = t >> 4, p = t & 15;
            float ssum = 0.f;
            #pragma unroll 8
            for (int gg = 0; gg < 64; ++gg) ssum += red[(oo * 64 + gg) * 17 + oo + p];
            mu_s[oo * 17 + p] = ssum / (rs_s[oo] + EPSV);
        }
        __syncthreads();
        // ---- pq partials ----
        #pragma unroll
        for (int p = 0; p < 16; ++p) {
            float ml = mu_s[o * 17 + p];
            float d0 = v[0][p] - ml; float pqp = rwl[0] * d0 * d0;
            float d1 = v[1][p] - ml; pqp = fmaf(rwl[1] * d1, d1, pqp);
            float d2 = v[2][p] - ml; pqp = fmaf(rwl[2] * d2, d2, pqp);
            float d3 = v[3][p] - ml; pqp = fmaf(rwl[3] * d3, d3, pqp);
            red[rowb + p] = pqp;
        }
        __syncthreads();
        if (t < 160) {
            int oo = t >> 4, p = t & 15;
            float ssum = 0.f;
            #pragma unroll 8
            for (int gg = 0; gg < 64; ++gg) ssum += red[(oo * 64 + gg) * 17 + oo + p];
            float sig = ssum / (rs_s[oo] + EPSV) + EPSV;
            float ls = logf(sig);
            lsig_s[oo * 17 + p] = ls;
            isig_s[oo * 17 + p] = 1.f / sig;
            float cost = (bu[oo] + 0.5f * ls) * rs_s[oo];
            #pragma unroll
            for (int mk = 1; mk <= 8; mk <<= 1) cost += __shfl_xor(cost, mk, 16);
            if (p == 0) {
                float ao = sigmoidf_(lam * (ba[oo] - cost));
                aout_s[oo] = ao; laout_s[oo] = logf(ao);
            }
        }
        __syncthreads();
        // ---- E-step ----
        if (it < 2) {
            float s0 = 0.f, s1 = 0.f, s2 = 0.f, s3 = 0.f;
            float cst = -8.f * LN_2PI;
            #pragma unroll
            for (int p = 0; p < 16; ++p) {
                float ml = mu_s[o * 17 + p];
                float isg = isig_s[o * 17 + p];
                cst -= 0.5f * lsig_s[o * 17 + p];
                float d0 = v[0][p] - ml; s0 = fmaf(d0 * d0, isg, s0);
                float d1 = v[1][p] - ml; s1 = fmaf(d1 * d1, isg, s1);
                float d2 = v[2][p] - ml; s2 = fmaf(d2 * d2, isg, s2);
                float d3 = v[3][p] - ml; s3 = fmaf(d3 * d3, isg, s3);
            }
            const float la = laout_s[o];
            rws[(g      ) * 11 + o] = fmaf(-0.5f, s0, cst) + la;
            rws[(g +  64) * 11 + o] = fmaf(-0.5f, s1, cst) + la;
            rws[(g + 128) * 11 + o] = fmaf(-0.5f, s2, cst) + la;
            rws[(g + 192) * 11 + o] = fmaf(-0.5f, s3, cst) + la;
        }
        __syncthreads();
    }
    if (t < 10) atomicAdd(&out[bidx * 10 + t], aout_s[t] * 0.04f);
}

extern "C" void kernel_launch(void* const* d_in, const int* in_sizes, int n_in,
                              void* d_out, int out_size, void* d_ws, size_t ws_size,
                              hipStream_t stream)
{
    const float* x           = (const float*)d_in[0];
    const float* conv_a_w    = (const float*)d_in[1];
    const float* conv_pose_w = (const float*)d_in[2];
    const float* bn_a_g = (const float*)d_in[3];
    const float* bn_a_b = (const float*)d_in[4];
    const float* bn_a_m = (const float*)d_in[5];
    const float* bn_a_v = (const float*)d_in[6];
    const float* bn_p_g = (const float*)d_in[7];
    const float* bn_p_b = (const float*)d_in[8];
    const float* bn_p_m = (const float*)d_in[9];
    const float* bn_p_v = (const float*)d_in[10];
    const float* em0_W  = (const float*)d_in[11];
    const float* em0_bu = (const float*)d_in[12];
    const float* em0_ba = (const float*)d_in[13];
    const float* bn0_g  = (const float*)d_in[14];
    const float* bn0_b  = (const float*)d_in[15];
    const float* bn0_m  = (const float*)d_in[16];
    const float* bn0_v  = (const float*)d_in[17];
    const float* em1_W  = (const float*)d_in[18];
    const float* em1_bu = (const float*)d_in[19];
    const float* em1_ba = (const float*)d_in[20];
    const float* bn1_g  = (const float*)d_in[21];
    const float* bn1_b  = (const float*)d_in[22];
    const float* bn1_m  = (const float*)d_in[23];
    const float* bn1_v  = (const float*)d_in[24];
    const float* fc_W   = (const float*)d_in[25];
    const float* fc_bu  = (const float*)d_in[26];
    const float* fc_ba  = (const float*)d_in[27];

    float* ws    = (float*)d_ws;
    float* a0    = ws;
    float* pose0 = a0 + 32768;
    float* a1    = pose0 + 524288;
    float* pose1 = a1 + 32768;
    float* a2    = pose1 + 524288;
    float* pose2 = a2 + 32768;
    float* out   = (float*)d_out;

    hipMemsetAsync(d_out, 0, (size_t)out_size * sizeof(float), stream);
    hipMemsetAsync(a0, 0, (size_t)(32768 + 524288) * sizeof(float), stream);
    k_conv3<<<256, 256, 0, stream>>>(x, conv_a_w, bn_a_g, bn_a_b, bn_a_m, bn_a_v,
                                     a0, 16, 1, 8, 32);
    k_conv3<<<2048, 256, 0, stream>>>(x, conv_pose_w, bn_p_g, bn_p_b, bn_p_m, bn_p_v,
                                      pose0, 256, 16, 4, 64);
    k_sig<<<128, 256, 0, stream>>>(a0, 32768);
    k_em_conv<<<2048, 768, 0, stream>>>(a0, pose0, em0_W, em0_bu, em0_ba,
                                        bn0_g, bn0_b, bn0_m, bn0_v, a1, pose1);
    k_em_conv<<<2048, 768, 0, stream>>>(a1, pose1, em1_W, em1_bu, em1_ba,
                                        bn1_g, bn1_b, bn1_m, bn1_v, a2, pose2);
    k_em_fc<<<800, 640, 0, stream>>>(a2, pose2, fc_W, fc_bu, fc_ba, out);
}

// Round 7
// 599.721 us; speedup vs baseline: 1.4098x; 1.1604x over previous
//
#include <hip/hip_runtime.h>

#define EPSV 1e-8f
#define BN_EPS 1e-5f
#define LN_2PI 1.8378770664093453f

__device__ __forceinline__ float sigmoidf_(float x) { return 1.0f / (1.0f + expf(-x)); }

// quad_perm DPP lane-xor (VALU pipe, no DS): 0xB1 = xor1 [1,0,3,2], 0x4E = xor2 [2,3,0,1]
template<int C>
__device__ __forceinline__ float dppx(float x) {
    int i = __builtin_amdgcn_mov_dpp(__builtin_bit_cast(int, x), C, 0xF, 0xF, true);
    return __builtin_bit_cast(float, i);
}

// ---------------- generic 3x3 pad1 conv on 8x8, split-K over ic chunks ----------------
__global__ __launch_bounds__(256) void k_conv3(
    const float* __restrict__ x, const float* __restrict__ w,
    const float* __restrict__ g, const float* __restrict__ b_,
    const float* __restrict__ m, const float* __restrict__ v,
    float* __restrict__ out, int OC, int nOcg, int nIcq, int icChunk)
{
    __shared__ float xs[6400];
    const int t = threadIdx.x;
    const int per_b = nOcg * nIcq;
    const int bidx = blockIdx.x / per_b;
    const int rem = blockIdx.x - bidx * per_b;
    const int ocg = rem / nIcq;
    const int icq = rem - ocg * nIcq;
    const int pix = t & 63, py = pix >> 3, px = pix & 7;
    const int ocb = t >> 6;
    const int ic0 = icq * icChunk;

    const int cells = icChunk * 100;
    for (int idx = t; idx < cells; idx += 256) {
        int icl = idx / 100;
        int c = idx - icl * 100;
        int iy = c / 10, ix = c - iy * 10;
        float val = 0.f;
        if (iy >= 1 && iy <= 8 && ix >= 1 && ix <= 8)
            val = x[(bidx * 256 + ic0 + icl) * 64 + (iy - 1) * 8 + (ix - 1)];
        xs[idx] = val;
    }
    __syncthreads();

    float acc[4] = {0.f, 0.f, 0.f, 0.f};
    for (int icl = 0; icl < icChunk; ++icl) {
        const float* wp = &w[((ocg * 16 + ocb) * 256 + ic0 + icl) * 9];
        const float* xr = &xs[icl * 100 + py * 10 + px];
        #pragma unroll
        for (int ky = 0; ky < 3; ++ky)
            #pragma unroll
            for (int kx = 0; kx < 3; ++kx) {
                float xv = xr[ky * 10 + kx];
                #pragma unroll
                for (int q = 0; q < 4; ++q)
                    acc[q] = fmaf(wp[q * 9216 + ky * 3 + kx], xv, acc[q]);
            }
    }
    #pragma unroll
    for (int q = 0; q < 4; ++q) {
        int oc = ocg * 16 + ocb + 4 * q;
        float sc = g[oc] * rsqrtf(v[oc] + BN_EPS);
        float add = acc[q] * sc;
        if (icq == 0) add += b_[oc] - m[oc] * sc;
        atomicAdd(&out[(bidx * OC + oc) * 64 + pix], add);
    }
}

__global__ void k_sig(float* __restrict__ a, int n)
{
    int i = blockIdx.x * 256 + threadIdx.x;
    if (i < n) a[i] = 1.f / (1.f + expf(-a[i]));
}

// ---------------- EM routing, conv-type (k=3, pad=1), A=B=16, P=16 ----------------
// grid: 32*64 blocks (b,l); block 768; lane = o*4 + kgl (o in lane bits 2-5, kg-low in 0-1).
// Thread owns k = (w_id*4+kgl) + 48s, s=0..2, at its o. Moment reduction over kg-in-wave
// = DPP quad_perm adds (VALU). Softmax over o = shfl masks 4..32 (2 reductions; renorm
// denominator is analytically av). E-step reads packed float2 (mu,isig) + scalar cst0.
__global__ __launch_bounds__(768) void k_em_conv(
    const float* __restrict__ a_in, const float* __restrict__ pose_in,
    const float* __restrict__ W, const float* __restrict__ bu, const float* __restrict__ ba,
    const float* __restrict__ bng, const float* __restrict__ bnb,
    const float* __restrict__ bnm, const float* __restrict__ bnv,
    float* __restrict__ a_out_g, float* __restrict__ pose_out)
{
    __shared__ float2 red2[3264] __attribute__((aligned(16)));  // (pm,pq) partials; aliased pc stage
    __shared__ float prsum[192];
    __shared__ float a_s[160];
    __shared__ float2 mi_s[272];      // (mu, 1/sig) [o*17+p]
    __shared__ float cst0_s[16], aout_s[16], laout_s[16];

    const int t = threadIdx.x;
    const int bidx = blockIdx.x >> 6;
    const int l = blockIdx.x & 63;
    const int y = l >> 3, xo = l & 7;
    const int kgl = t & 3;
    const int o = (t >> 2) & 15;
    const int w_id = t >> 6;          // 0..11
    const int kg = w_id * 4 + kgl;    // 0..47

    float* pc_s = reinterpret_cast<float*>(red2);

    for (int idx = t; idx < 2304; idx += 768) {
        int k = idx >> 4, p = idx & 15;
        int a = k & 15, kk = k >> 4;
        int iy = y + kk / 3 - 1, ix = xo + (kk % 3) - 1;
        float val = 0.f;
        if (iy >= 0 && iy < 8 && ix >= 0 && ix < 8)
            val = pose_in[(bidx * 256 + a * 16 + p) * 64 + iy * 8 + ix];
        pc_s[k * 20 + p] = val;
    }
    if (t < 144) {
        int a = t & 15, kk = t >> 4;
        int iy = y + kk / 3 - 1, ix = xo + (kk % 3) - 1;
        a_s[t] = (iy >= 0 && iy < 8 && ix >= 0 && ix < 8) ? a_in[(bidx * 16 + a) * 64 + iy * 8 + ix] : 0.f;
    }
    __syncthreads();

    // ---- votes: stream over h ----
    float v[3][16];
    const float4* W4 = reinterpret_cast<const float4*>(W);
    #pragma unroll
    for (int s = 0; s < 3; ++s) {
        int k = kg + 48 * s;
        float pcl[16];
        #pragma unroll
        for (int c = 0; c < 4; ++c) {
            float4 p4 = *reinterpret_cast<const float4*>(&pc_s[k * 20 + c * 4]);
            pcl[c * 4 + 0] = p4.x; pcl[c * 4 + 1] = p4.y; pcl[c * 4 + 2] = p4.z; pcl[c * 4 + 3] = p4.w;
        }
        #pragma unroll
        for (int p = 0; p < 16; ++p) v[s][p] = 0.f;
        #pragma unroll
        for (int h = 0; h < 4; ++h) {
            float4 wr = W4[(k * 16 + o) * 4 + h];
            #pragma unroll
            for (int i = 0; i < 4; ++i) {
                float a = pcl[i * 4 + h];
                v[s][i * 4 + 0] = fmaf(a, wr.x, v[s][i * 4 + 0]);
                v[s][i * 4 + 1] = fmaf(a, wr.y, v[s][i * 4 + 1]);
                v[s][i * 4 + 2] = fmaf(a, wr.z, v[s][i * 4 + 2]);
                v[s][i * 4 + 3] = fmaf(a, wr.w, v[s][i * 4 + 3]);
            }
        }
    }
    float afac[3];
    #pragma unroll
    for (int s = 0; s < 3; ++s) { float av = a_s[kg + 48 * s]; afac[s] = av / (av + EPSV); }
    __syncthreads();  // pc_s dead; red2 reused

    float lg[3] = {0.f, 0.f, 0.f};
    for (int it = 0; it < 3; ++it) {
        float lam = (it == 0) ? 5.0e-4f : ((it == 1) ? 9.75e-4f : 1.42625e-3f);
        // ---- softmax over o (lanes stride 4) ----
        float rw[3];
        if (it == 0) {
            #pragma unroll
            for (int s = 0; s < 3; ++s) rw[s] = 0.0625f * afac[s];
        } else {
            #pragma unroll
            for (int s = 0; s < 3; ++s) {
                float mx = lg[s];
                #pragma unroll
                for (int mk = 4; mk <= 32; mk <<= 1) mx = fmaxf(mx, __shfl_xor(mx, mk, 64));
                float e = expf(lg[s] - mx);
                float den = e;
                #pragma unroll
                for (int mk = 4; mk <= 32; mk <<= 1) den += __shfl_xor(den, mk, 64);
                rw[s] = (e / den) * afac[s];
            }
        }
        // ---- moments: per-p scalars, DPP quad reduce over kgl, float2 store ----
        float prw = rw[0] + rw[1] + rw[2];
        prw += dppx<0xB1>(prw); prw += dppx<0x4E>(prw);
        const int row = (w_id * 16 + o) * 17;
        if (kgl == 0) prsum[w_id * 16 + o] = prw;
        #pragma unroll
        for (int p = 0; p < 16; ++p) {
            float v0 = v[0][p], v1 = v[1][p], v2 = v[2][p];
            float pmp = rw[0] * v0; pmp = fmaf(rw[1], v1, pmp); pmp = fmaf(rw[2], v2, pmp);
            float pqp = rw[0] * v0 * v0; pqp = fmaf(rw[1] * v1, v1, pqp); pqp = fmaf(rw[2] * v2, v2, pqp);
            pmp += dppx<0xB1>(pmp); pmp += dppx<0x4E>(pmp);
            pqp += dppx<0xB1>(pqp); pqp += dppx<0x4E>(pqp);
            if (kgl == 0) red2[row + p] = make_float2(pmp, pqp);
        }
        __syncthreads();
        // ---- stage-2: 12 partials -> mu, isig, cst0, a_out ----
        if (t < 256) {
            int oo = t >> 4, p = t & 15;
            float spm = 0.f, spq = 0.f, srs = 0.f;
            #pragma unroll
            for (int u = 0; u < 12; ++u) {
                float2 r2 = red2[(u * 16 + oo) * 17 + p];
                spm += r2.x; spq += r2.y;
                srs += prsum[u * 16 + oo];
            }
            float invr = 1.f / (srs + EPSV);
            float mu = spm * invr;
            float beta = srs * invr;
            float sig = fmaf(-(2.f - beta) * mu, mu, spq * invr) + EPSV;
            float ls = logf(sig);
            mi_s[oo * 17 + p] = make_float2(mu, 1.f / sig);
            float sumls = ls;
            #pragma unroll
            for (int mk = 1; mk <= 8; mk <<= 1) sumls += __shfl_xor(sumls, mk, 64);
            if (p == 0) {
                float cost = srs * fmaf(0.5f, sumls, 16.f * bu[oo]);
                float ao = sigmoidf_(lam * (ba[oo] - cost));
                aout_s[oo] = ao; laout_s[oo] = logf(ao);
                cst0_s[oo] = fmaf(-0.5f, sumls, -8.f * LN_2PI);
            }
        }
        __syncthreads();
        // ---- E-step ----
        if (it < 2) {
            float s0 = 0.f, s1 = 0.f, s2 = 0.f;
            #pragma unroll
            for (int p = 0; p < 16; ++p) {
                float2 mi = mi_s[o * 17 + p];
                float d0 = v[0][p] - mi.x; s0 = fmaf(d0 * d0, mi.y, s0);
                float d1 = v[1][p] - mi.x; s1 = fmaf(d1 * d1, mi.y, s1);
                float d2 = v[2][p] - mi.x; s2 = fmaf(d2 * d2, mi.y, s2);
            }
            float cb = cst0_s[o] + laout_s[o];
            lg[0] = fmaf(-0.5f, s0, cb);
            lg[1] = fmaf(-0.5f, s1, cb);
            lg[2] = fmaf(-0.5f, s2, cb);
        }
    }
    if (t < 256) {
        float sc = bng[t] * rsqrtf(bnv[t] + BN_EPS);
        float mu = mi_s[(t >> 4) * 17 + (t & 15)].x;
        pose_out[(bidx * 256 + t) * 64 + l] = (mu - bnm[t]) * sc + bnb[t];
    }
    if (t < 16) a_out_g[(bidx * 16 + t) * 64 + l] = aout_s[t];
}

// ---------------- EM routing, FC-type (k=4, pad=0), A=16, B=10, P=16 ----------------
__global__ __launch_bounds__(640) void k_em_fc(
    const float* __restrict__ a_in, const float* __restrict__ pose_in,
    const float* __restrict__ W, const float* __restrict__ bu, const float* __restrict__ ba,
    float* __restrict__ out)
{
    __shared__ float red[10896] __attribute__((aligned(16)));
    __shared__ float rws[2816];
    __shared__ float ain_s[256];
    __shared__ float mu_s[176], lsig_s[176], isig_s[176];
    __shared__ float rs_s[16], aout_s[16], laout_s[16];

    const int t = threadIdx.x;
    const int bidx = blockIdx.x / 25;
    const int l = blockIdx.x % 25;
    const int y = l / 5, xo = l % 5;
    const int o = t >> 6;
    const int g = t & 63;

    float* pcs = red;
    for (int idx = t; idx < 4096; idx += 640) {
        int k = idx >> 4, p = idx & 15;
        int a = k & 15, kk = k >> 4;
        int iy = y + (kk >> 2), ix = xo + (kk & 3);
        pcs[k * 20 + p] = pose_in[((bidx * 256 + a * 16 + p) << 6) + iy * 8 + ix];
    }
    if (t < 256) {
        int a = t & 15, kk = t >> 4;
        int iy = y + (kk >> 2), ix = xo + (kk & 3);
        ain_s[t] = a_in[((bidx * 16 + a) << 6) + iy * 8 + ix];
    }
    __syncthreads();

    float v[4][16];
    const float4* W4 = reinterpret_cast<const float4*>(W);
    #pragma unroll
    for (int s = 0; s < 4; ++s) {
        int k = g + 64 * s;
        float pcl[16];
        #pragma unroll
        for (int c = 0; c < 4; ++c) {
            float4 p4 = *reinterpret_cast<const float4*>(&pcs[k * 20 + c * 4]);
            pcl[c * 4 + 0] = p4.x; pcl[c * 4 + 1] = p4.y; pcl[c * 4 + 2] = p4.z; pcl[c * 4 + 3] = p4.w;
        }
        #pragma unroll
        for (int p = 0; p < 16; ++p) v[s][p] = 0.f;
        #pragma unroll
        for (int h = 0; h < 4; ++h) {
            float4 wr = W4[(k * 10 + o) * 4 + h];
            #pragma unroll
            for (int i = 0; i < 4; ++i) {
                float a = pcl[i * 4 + h];
                v[s][i * 4 + 0] = fmaf(a, wr.x, v[s][i * 4 + 0]);
                v[s][i * 4 + 1] = fmaf(a, wr.y, v[s][i * 4 + 1]);
                v[s][i * 4 + 2] = fmaf(a, wr.z, v[s][i * 4 + 2]);
                v[s][i * 4 + 3] = fmaf(a, wr.w, v[s][i * 4 + 3]);
            }
        }
    }
    __syncthreads();

    const int rowb = t * 17 + o;
    for (int it = 0; it < 3; ++it) {
        float lam = (it == 0) ? 5.0e-4f : ((it == 1) ? 9.75e-4f : 1.42625e-3f);
        if (t < 256) {
            float av = ain_s[t];
            if (it == 0) {
                float val = 0.1f * av / (av + EPSV);
                #pragma unroll
                for (int oo = 0; oo < 10; ++oo) rws[t * 11 + oo] = val;
            } else {
                float mx = -1e30f;
                #pragma unroll
                for (int oo = 0; oo < 10; ++oo) mx = fmaxf(mx, rws[t * 11 + oo]);
                float den = 0.f;
                #pragma unroll
                for (int oo = 0; oo < 10; ++oo) den += expf(rws[t * 11 + oo] - mx);
                float sc = av / (den * (av + EPSV));
                #pragma unroll
                for (int oo = 0; oo < 10; ++oo) rws[t * 11 + oo] = expf(rws[t * 11 + oo] - mx) * sc;
            }
        }
        __syncthreads();
        float rwl[4]; float prs = 0.f;
        #pragma unroll
        for (int s = 0; s < 4; ++s) { rwl[s] = rws[(g + 64 * s) * 11 + o]; prs += rwl[s]; }
        #pragma unroll
        for (int off = 32; off > 0; off >>= 1) prs += __shfl_xor(prs, off, 64);
        if (g == 0) rs_s[o] = prs;
        #pragma unroll
        for (int p = 0; p < 16; ++p) {
            float pmp = rwl[0] * v[0][p];
            pmp = fmaf(rwl[1], v[1][p], pmp);
            pmp = fmaf(rwl[2], v[2][p], pmp);
            pmp = fmaf(rwl[3], v[3][p], pmp);
            red[rowb + p] = pmp;
        }
        __syncthreads();
        if (t < 160) {
            int oo = t >> 4, p = t & 15;
            float ssum = 0.f;
            #pragma unroll 8
            for (int gg = 0; gg < 64; ++gg) ssum += red[(oo * 64 + gg) * 17 + oo + p];
            mu_s[oo * 17 + p] = ssum / (rs_s[oo] + EPSV);
        }
        __syncthreads();
        #pragma unroll
        for (int p = 0; p < 16; ++p) {
            float ml = mu_s[o * 17 + p];
            float d0 = v[0][p] - ml; float pqp = rwl[0] * d0 * d0;
            float d1 = v[1][p] - ml; pqp = fmaf(rwl[1] * d1, d1, pqp);
            float d2 = v[2][p] - ml; pqp = fmaf(rwl[2] * d2, d2, pqp);
            float d3 = v[3][p] - ml; pqp = fmaf(rwl[3] * d3, d3, pqp);
            red[rowb + p] = pqp;
        }
        __syncthreads();
        if (t < 160) {
            int oo = t >> 4, p = t & 15;
            float ssum = 0.f;
            #pragma unroll 8
            for (int gg = 0; gg < 64; ++gg) ssum += red[(oo * 64 + gg) * 17 + oo + p];
            float sig = ssum / (rs_s[oo] + EPSV) + EPSV;
            float ls = logf(sig);
            lsig_s[oo * 17 + p] = ls;
            isig_s[oo * 17 + p] = 1.f / sig;
            float cost = (bu[oo] + 0.5f * ls) * rs_s[oo];
            #pragma unroll
            for (int mk = 1; mk <= 8; mk <<= 1) cost += __shfl_xor(cost, mk, 16);
            if (p == 0) {
                float ao = sigmoidf_(lam * (ba[oo] - cost));
                aout_s[oo] = ao; laout_s[oo] = logf(ao);
            }
        }
        __syncthreads();
        if (it < 2) {
            float s0 = 0.f, s1 = 0.f, s2 = 0.f, s3 = 0.f;
            float cst = -8.f * LN_2PI;
            #pragma unroll
            for (int p = 0; p < 16; ++p) {
                float ml = mu_s[o * 17 + p];
                float isg = isig_s[o * 17 + p];
                cst -= 0.5f * lsig_s[o * 17 + p];
                float d0 = v[0][p] - ml; s0 = fmaf(d0 * d0, isg, s0);
                float d1 = v[1][p] - ml; s1 = fmaf(d1 * d1, isg, s1);
                float d2 = v[2][p] - ml; s2 = fmaf(d2 * d2, isg, s2);
                float d3 = v[3][p] - ml; s3 = fmaf(d3 * d3, isg, s3);
            }
            const float la = laout_s[o];
            rws[(g      ) * 11 + o] = fmaf(-0.5f, s0, cst) + la;
            rws[(g +  64) * 11 + o] = fmaf(-0.5f, s1, cst) + la;
            rws[(g + 128) * 11 + o] = fmaf(-0.5f, s2, cst) + la;
            rws[(g + 192) * 11 + o] = fmaf(-0.5f, s3, cst) + la;
        }
        __syncthreads();
    }
    if (t < 10) atomicAdd(&out[bidx * 10 + t], aout_s[t] * 0.04f);
}

extern "C" void kernel_launch(void* const* d_in, const int* in_sizes, int n_in,
                              void* d_out, int out_size, void* d_ws, size_t ws_size,
                              hipStream_t stream)
{
    const float* x           = (const float*)d_in[0];
    const float* conv_a_w    = (const float*)d_in[1];
    const float* conv_pose_w = (const float*)d_in[2];
    const float* bn_a_g = (const float*)d_in[3];
    const float* bn_a_b = (const float*)d_in[4];
    const float* bn_a_m = (const float*)d_in[5];
    const float* bn_a_v = (const float*)d_in[6];
    const float* bn_p_g = (const float*)d_in[7];
    const float* bn_p_b = (const float*)d_in[8];
    const float* bn_p_m = (const float*)d_in[9];
    const float* bn_p_v = (const float*)d_in[10];
    const float* em0_W  = (const float*)d_in[11];
    const float* em0_bu = (const float*)d_in[12];
    const float* em0_ba = (const float*)d_in[13];
    const float* bn0_g  = (const float*)d_in[14];
    const float* bn0_b  = (const float*)d_in[15];
    const float* bn0_m  = (const float*)d_in[16];
    const float* bn0_v  = (const float*)d_in[17];
    const float* em1_W  = (const float*)d_in[18];
    const float* em1_bu = (const float*)d_in[19];
    const float* em1_ba = (const float*)d_in[20];
    const float* bn1_g  = (const float*)d_in[21];
    const float* bn1_b  = (const float*)d_in[22];
    const float* bn1_m  = (const float*)d_in[23];
    const float* bn1_v  = (const float*)d_in[24];
    const float* fc_W   = (const float*)d_in[25];
    const float* fc_bu  = (const float*)d_in[26];
    const float* fc_ba  = (const float*)d_in[27];

    float* ws    = (float*)d_ws;
    float* a0    = ws;
    float* pose0 = a0 + 32768;
    float* a1    = pose0 + 524288;
    float* pose1 = a1 + 32768;
    float* a2    = pose1 + 524288;
    float* pose2 = a2 + 32768;
    float* out   = (float*)d_out;

    hipMemsetAsync(d_out, 0, (size_t)out_size * sizeof(float), stream);
    hipMemsetAsync(a0, 0, (size_t)(32768 + 524288) * sizeof(float), stream);
    k_conv3<<<256, 256, 0, stream>>>(x, conv_a_w, bn_a_g, bn_a_b, bn_a_m, bn_a_v,
                                     a0, 16, 1, 8, 32);
    k_conv3<<<2048, 256, 0, stream>>>(x, conv_pose_w, bn_p_g, bn_p_b, bn_p_m, bn_p_v,
                                      pose0, 256, 16, 4, 64);
    k_sig<<<128, 256, 0, stream>>>(a0, 32768);
    k_em_conv<<<2048, 768, 0, stream>>>(a0, pose0, em0_W, em0_bu, em0_ba,
                                        bn0_g, bn0_b, bn0_m, bn0_v, a1, pose1);
    k_em_conv<<<2048, 768, 0, stream>>>(a1, pose1, em1_W, em1_bu, em1_ba,
                                        bn1_g, bn1_b, bn1_m, bn1_v, a2, pose2);
    k_em_fc<<<800, 640, 0, stream>>>(a2, pose2, fc_W, fc_bu, fc_ba, out);
}

// Round 8
// 513.821 us; speedup vs baseline: 1.6455x; 1.1672x over previous
//
#include <hip/hip_runtime.h>

#define EPSV 1e-8f
#define BN_EPS 1e-5f
#define LN_2PI 1.8378770664093453f

__device__ __forceinline__ float sigmoidf_(float x) { return 1.0f / (1.0f + expf(-x)); }

// quad_perm DPP lane-xor (VALU pipe, no DS): 0xB1 = xor1 [1,0,3,2], 0x4E = xor2 [2,3,0,1]
template<int C>
__device__ __forceinline__ float dppx(float x) {
    int i = __builtin_amdgcn_mov_dpp(__builtin_bit_cast(int, x), C, 0xF, 0xF, true);
    return __builtin_bit_cast(float, i);
}

// ---------------- generic 3x3 pad1 conv on 8x8, split-K over ic chunks ----------------
// block 256 = 64 pix x 4 ocb; thread computes NACC oc (ocb + 4q). Weight addressing is
// forced wave-uniform via readfirstlane(ocb) -> scalar s_load on the scalar pipe.
// LDS tile: 10 rows x stride 12 per ic -> 12y+x mod 32 hits each bank exactly twice
// for every tap (2-way = free). Epilogue: atomicAdd with BN affine folded.
template<int NACC>
__global__ __launch_bounds__(256, 4) void k_conv3(
    const float* __restrict__ x, const float* __restrict__ w,
    const float* __restrict__ g, const float* __restrict__ b_,
    const float* __restrict__ m, const float* __restrict__ v,
    float* __restrict__ out, int OC, int nOcg, int nIcq, int icChunk)
{
    __shared__ float xs[32 * 120];
    const int t = threadIdx.x;
    const int per_b = nOcg * nIcq;
    const int bidx = blockIdx.x / per_b;
    const int rem = blockIdx.x - bidx * per_b;
    const int ocg = rem / nIcq;
    const int icq = rem - ocg * nIcq;
    const int pix = t & 63, py = pix >> 3, px = pix & 7;
    const int ocb_u = __builtin_amdgcn_readfirstlane(t >> 6);
    const int ic0 = icq * icChunk;

    const int cells = icChunk * 120;
    for (int idx = t; idx < cells; idx += 256) {
        int icl = idx / 120;
        int c = idx - icl * 120;
        int iy = c / 12, ix = c - iy * 12;
        float val = 0.f;
        if (iy >= 1 && iy <= 8 && ix >= 1 && ix <= 8)
            val = x[(bidx * 256 + ic0 + icl) * 64 + (iy - 1) * 8 + (ix - 1)];
        xs[idx] = val;
    }
    __syncthreads();

    const int oc_base = ocg * 4 * NACC + ocb_u;
    const float* wb = w + ((size_t)(oc_base * 256 + ic0)) * 9;

    float acc[NACC];
    #pragma unroll
    for (int q = 0; q < NACC; ++q) acc[q] = 0.f;

    for (int icl = 0; icl < icChunk; ++icl) {
        const float* xr = &xs[icl * 120 + py * 12 + px];
        const float* wr = &wb[icl * 9];
        #pragma unroll
        for (int ky = 0; ky < 3; ++ky)
            #pragma unroll
            for (int kx = 0; kx < 3; ++kx) {
                float xv = xr[ky * 12 + kx];
                #pragma unroll
                for (int q = 0; q < NACC; ++q)
                    acc[q] = fmaf(wr[q * 9216 + ky * 3 + kx], xv, acc[q]);  // 4*256*9 = 9216
            }
    }
    #pragma unroll
    for (int q = 0; q < NACC; ++q) {
        int oc = oc_base + 4 * q;
        float sc = g[oc] * rsqrtf(v[oc] + BN_EPS);
        float add = acc[q] * sc;
        if (icq == 0) add += b_[oc] - m[oc] * sc;
        atomicAdd(&out[(bidx * OC + oc) * 64 + pix], add);
    }
}

__global__ void k_sig(float* __restrict__ a, int n)
{
    int i = blockIdx.x * 256 + threadIdx.x;
    if (i < n) a[i] = 1.f / (1.f + expf(-a[i]));
}

// ---------------- EM routing, conv-type (k=3, pad=1), A=B=16, P=16 ----------------
__global__ __launch_bounds__(768) void k_em_conv(
    const float* __restrict__ a_in, const float* __restrict__ pose_in,
    const float* __restrict__ W, const float* __restrict__ bu, const float* __restrict__ ba,
    const float* __restrict__ bng, const float* __restrict__ bnb,
    const float* __restrict__ bnm, const float* __restrict__ bnv,
    float* __restrict__ a_out_g, float* __restrict__ pose_out)
{
    __shared__ float2 red2[3264] __attribute__((aligned(16)));
    __shared__ float prsum[192];
    __shared__ float a_s[160];
    __shared__ float2 mi_s[272];
    __shared__ float cst0_s[16], aout_s[16], laout_s[16];

    const int t = threadIdx.x;
    const int bidx = blockIdx.x >> 6;
    const int l = blockIdx.x & 63;
    const int y = l >> 3, xo = l & 7;
    const int kgl = t & 3;
    const int o = (t >> 2) & 15;
    const int w_id = t >> 6;
    const int kg = w_id * 4 + kgl;

    float* pc_s = reinterpret_cast<float*>(red2);

    for (int idx = t; idx < 2304; idx += 768) {
        int k = idx >> 4, p = idx & 15;
        int a = k & 15, kk = k >> 4;
        int iy = y + kk / 3 - 1, ix = xo + (kk % 3) - 1;
        float val = 0.f;
        if (iy >= 0 && iy < 8 && ix >= 0 && ix < 8)
            val = pose_in[(bidx * 256 + a * 16 + p) * 64 + iy * 8 + ix];
        pc_s[k * 20 + p] = val;
    }
    if (t < 144) {
        int a = t & 15, kk = t >> 4;
        int iy = y + kk / 3 - 1, ix = xo + (kk % 3) - 1;
        a_s[t] = (iy >= 0 && iy < 8 && ix >= 0 && ix < 8) ? a_in[(bidx * 16 + a) * 64 + iy * 8 + ix] : 0.f;
    }
    __syncthreads();

    float v[3][16];
    const float4* W4 = reinterpret_cast<const float4*>(W);
    #pragma unroll
    for (int s = 0; s < 3; ++s) {
        int k = kg + 48 * s;
        float pcl[16];
        #pragma unroll
        for (int c = 0; c < 4; ++c) {
            float4 p4 = *reinterpret_cast<const float4*>(&pc_s[k * 20 + c * 4]);
            pcl[c * 4 + 0] = p4.x; pcl[c * 4 + 1] = p4.y; pcl[c * 4 + 2] = p4.z; pcl[c * 4 + 3] = p4.w;
        }
        #pragma unroll
        for (int p = 0; p < 16; ++p) v[s][p] = 0.f;
        #pragma unroll
        for (int h = 0; h < 4; ++h) {
            float4 wr = W4[(k * 16 + o) * 4 + h];
            #pragma unroll
            for (int i = 0; i < 4; ++i) {
                float a = pcl[i * 4 + h];
                v[s][i * 4 + 0] = fmaf(a, wr.x, v[s][i * 4 + 0]);
                v[s][i * 4 + 1] = fmaf(a, wr.y, v[s][i * 4 + 1]);
                v[s][i * 4 + 2] = fmaf(a, wr.z, v[s][i * 4 + 2]);
                v[s][i * 4 + 3] = fmaf(a, wr.w, v[s][i * 4 + 3]);
            }
        }
    }
    float afac[3];
    #pragma unroll
    for (int s = 0; s < 3; ++s) { float av = a_s[kg + 48 * s]; afac[s] = av / (av + EPSV); }
    __syncthreads();

    float lg[3] = {0.f, 0.f, 0.f};
    for (int it = 0; it < 3; ++it) {
        float lam = (it == 0) ? 5.0e-4f : ((it == 1) ? 9.75e-4f : 1.42625e-3f);
        float rw[3];
        if (it == 0) {
            #pragma unroll
            for (int s = 0; s < 3; ++s) rw[s] = 0.0625f * afac[s];
        } else {
            #pragma unroll
            for (int s = 0; s < 3; ++s) {
                float mx = lg[s];
                #pragma unroll
                for (int mk = 4; mk <= 32; mk <<= 1) mx = fmaxf(mx, __shfl_xor(mx, mk, 64));
                float e = expf(lg[s] - mx);
                float den = e;
                #pragma unroll
                for (int mk = 4; mk <= 32; mk <<= 1) den += __shfl_xor(den, mk, 64);
                rw[s] = (e / den) * afac[s];
            }
        }
        float prw = rw[0] + rw[1] + rw[2];
        prw += dppx<0xB1>(prw); prw += dppx<0x4E>(prw);
        const int row = (w_id * 16 + o) * 17;
        if (kgl == 0) prsum[w_id * 16 + o] = prw;
        #pragma unroll
        for (int p = 0; p < 16; ++p) {
            float v0 = v[0][p], v1 = v[1][p], v2 = v[2][p];
            float pmp = rw[0] * v0; pmp = fmaf(rw[1], v1, pmp); pmp = fmaf(rw[2], v2, pmp);
            float pqp = rw[0] * v0 * v0; pqp = fmaf(rw[1] * v1, v1, pqp); pqp = fmaf(rw[2] * v2, v2, pqp);
            pmp += dppx<0xB1>(pmp); pmp += dppx<0x4E>(pmp);
            pqp += dppx<0xB1>(pqp); pqp += dppx<0x4E>(pqp);
            if (kgl == 0) red2[row + p] = make_float2(pmp, pqp);
        }
        __syncthreads();
        if (t < 256) {
            int oo = t >> 4, p = t & 15;
            float spm = 0.f, spq = 0.f, srs = 0.f;
            #pragma unroll
            for (int u = 0; u < 12; ++u) {
                float2 r2 = red2[(u * 16 + oo) * 17 + p];
                spm += r2.x; spq += r2.y;
                srs += prsum[u * 16 + oo];
            }
            float invr = 1.f / (srs + EPSV);
            float mu = spm * invr;
            float beta = srs * invr;
            float sig = fmaf(-(2.f - beta) * mu, mu, spq * invr) + EPSV;
            float ls = logf(sig);
            mi_s[oo * 17 + p] = make_float2(mu, 1.f / sig);
            float sumls = ls;
            #pragma unroll
            for (int mk = 1; mk <= 8; mk <<= 1) sumls += __shfl_xor(sumls, mk, 64);
            if (p == 0) {
                float cost = srs * fmaf(0.5f, sumls, 16.f * bu[oo]);
                float ao = sigmoidf_(lam * (ba[oo] - cost));
                aout_s[oo] = ao; laout_s[oo] = logf(ao);
                cst0_s[oo] = fmaf(-0.5f, sumls, -8.f * LN_2PI);
            }
        }
        __syncthreads();
        if (it < 2) {
            float s0 = 0.f, s1 = 0.f, s2 = 0.f;
            #pragma unroll
            for (int p = 0; p < 16; ++p) {
                float2 mi = mi_s[o * 17 + p];
                float d0 = v[0][p] - mi.x; s0 = fmaf(d0 * d0, mi.y, s0);
                float d1 = v[1][p] - mi.x; s1 = fmaf(d1 * d1, mi.y, s1);
                float d2 = v[2][p] - mi.x; s2 = fmaf(d2 * d2, mi.y, s2);
            }
            float cb = cst0_s[o] + laout_s[o];
            lg[0] = fmaf(-0.5f, s0, cb);
            lg[1] = fmaf(-0.5f, s1, cb);
            lg[2] = fmaf(-0.5f, s2, cb);
        }
    }
    if (t < 256) {
        float sc = bng[t] * rsqrtf(bnv[t] + BN_EPS);
        float mu = mi_s[(t >> 4) * 17 + (t & 15)].x;
        pose_out[(bidx * 256 + t) * 64 + l] = (mu - bnm[t]) * sc + bnb[t];
    }
    if (t < 16) a_out_g[(bidx * 16 + t) * 64 + l] = aout_s[t];
}

// ---------------- EM routing, FC-type (k=4, pad=0), A=16, B=10, P=16 ----------------
__global__ __launch_bounds__(640) void k_em_fc(
    const float* __restrict__ a_in, const float* __restrict__ pose_in,
    const float* __restrict__ W, const float* __restrict__ bu, const float* __restrict__ ba,
    float* __restrict__ out)
{
    __shared__ float red[10896] __attribute__((aligned(16)));
    __shared__ float rws[2816];
    __shared__ float ain_s[256];
    __shared__ float mu_s[176], lsig_s[176], isig_s[176];
    __shared__ float rs_s[16], aout_s[16], laout_s[16];

    const int t = threadIdx.x;
    const int bidx = blockIdx.x / 25;
    const int l = blockIdx.x % 25;
    const int y = l / 5, xo = l % 5;
    const int o = t >> 6;
    const int g = t & 63;

    float* pcs = red;
    for (int idx = t; idx < 4096; idx += 640) {
        int k = idx >> 4, p = idx & 15;
        int a = k & 15, kk = k >> 4;
        int iy = y + (kk >> 2), ix = xo + (kk & 3);
        pcs[k * 20 + p] = pose_in[((bidx * 256 + a * 16 + p) << 6) + iy * 8 + ix];
    }
    if (t < 256) {
        int a = t & 15, kk = t >> 4;
        int iy = y + (kk >> 2), ix = xo + (kk & 3);
        ain_s[t] = a_in[((bidx * 16 + a) << 6) + iy * 8 + ix];
    }
    __syncthreads();

    float v[4][16];
    const float4* W4 = reinterpret_cast<const float4*>(W);
    #pragma unroll
    for (int s = 0; s < 4; ++s) {
        int k = g + 64 * s;
        float pcl[16];
        #pragma unroll
        for (int c = 0; c < 4; ++c) {
            float4 p4 = *reinterpret_cast<const float4*>(&pcs[k * 20 + c * 4]);
            pcl[c * 4 + 0] = p4.x; pcl[c * 4 + 1] = p4.y; pcl[c * 4 + 2] = p4.z; pcl[c * 4 + 3] = p4.w;
        }
        #pragma unroll
        for (int p = 0; p < 16; ++p) v[s][p] = 0.f;
        #pragma unroll
        for (int h = 0; h < 4; ++h) {
            float4 wr = W4[(k * 10 + o) * 4 + h];
            #pragma unroll
            for (int i = 0; i < 4; ++i) {
                float a = pcl[i * 4 + h];
                v[s][i * 4 + 0] = fmaf(a, wr.x, v[s][i * 4 + 0]);
                v[s][i * 4 + 1] = fmaf(a, wr.y, v[s][i * 4 + 1]);
                v[s][i * 4 + 2] = fmaf(a, wr.z, v[s][i * 4 + 2]);
                v[s][i * 4 + 3] = fmaf(a, wr.w, v[s][i * 4 + 3]);
            }
        }
    }
    __syncthreads();

    const int rowb = t * 17 + o;
    for (int it = 0; it < 3; ++it) {
        float lam = (it == 0) ? 5.0e-4f : ((it == 1) ? 9.75e-4f : 1.42625e-3f);
        if (t < 256) {
            float av = ain_s[t];
            if (it == 0) {
                float val = 0.1f * av / (av + EPSV);
                #pragma unroll
                for (int oo = 0; oo < 10; ++oo) rws[t * 11 + oo] = val;
            } else {
                float mx = -1e30f;
                #pragma unroll
                for (int oo = 0; oo < 10; ++oo) mx = fmaxf(mx, rws[t * 11 + oo]);
                float den = 0.f;
                #pragma unroll
                for (int oo = 0; oo < 10; ++oo) den += expf(rws[t * 11 + oo] - mx);
                float sc = av / (den * (av + EPSV));
                #pragma unroll
                for (int oo = 0; oo < 10; ++oo) rws[t * 11 + oo] = expf(rws[t * 11 + oo] - mx) * sc;
            }
        }
        __syncthreads();
        float rwl[4]; float prs = 0.f;
        #pragma unroll
        for (int s = 0; s < 4; ++s) { rwl[s] = rws[(g + 64 * s) * 11 + o]; prs += rwl[s]; }
        #pragma unroll
        for (int off = 32; off > 0; off >>= 1) prs += __shfl_xor(prs, off, 64);
        if (g == 0) rs_s[o] = prs;
        #pragma unroll
        for (int p = 0; p < 16; ++p) {
            float pmp = rwl[0] * v[0][p];
            pmp = fmaf(rwl[1], v[1][p], pmp);
            pmp = fmaf(rwl[2], v[2][p], pmp);
            pmp = fmaf(rwl[3], v[3][p], pmp);
            red[rowb + p] = pmp;
        }
        __syncthreads();
        if (t < 160) {
            int oo = t >> 4, p = t & 15;
            float ssum = 0.f;
            #pragma unroll 8
            for (int gg = 0; gg < 64; ++gg) ssum += red[(oo * 64 + gg) * 17 + oo + p];
            mu_s[oo * 17 + p] = ssum / (rs_s[oo] + EPSV);
        }
        __syncthreads();
        #pragma unroll
        for (int p = 0; p < 16; ++p) {
            float ml = mu_s[o * 17 + p];
            float d0 = v[0][p] - ml; float pqp = rwl[0] * d0 * d0;
            float d1 = v[1][p] - ml; pqp = fmaf(rwl[1] * d1, d1, pqp);
            float d2 = v[2][p] - ml; pqp = fmaf(rwl[2] * d2, d2, pqp);
            float d3 = v[3][p] - ml; pqp = fmaf(rwl[3] * d3, d3, pqp);
            red[rowb + p] = pqp;
        }
        __syncthreads();
        if (t < 160) {
            int oo = t >> 4, p = t & 15;
            float ssum = 0.f;
            #pragma unroll 8
            for (int gg = 0; gg < 64; ++gg) ssum += red[(oo * 64 + gg) * 17 + oo + p];
            float sig = ssum / (rs_s[oo] + EPSV) + EPSV;
            float ls = logf(sig);
            lsig_s[oo * 17 + p] = ls;
            isig_s[oo * 17 + p] = 1.f / sig;
            float cost = (bu[oo] + 0.5f * ls) * rs_s[oo];
            #pragma unroll
            for (int mk = 1; mk <= 8; mk <<= 1) cost += __shfl_xor(cost, mk, 16);
            if (p == 0) {
                float ao = sigmoidf_(lam * (ba[oo] - cost));
                aout_s[oo] = ao; laout_s[oo] = logf(ao);
            }
        }
        __syncthreads();
        if (it < 2) {
            float s0 = 0.f, s1 = 0.f, s2 = 0.f, s3 = 0.f;
            float cst = -8.f * LN_2PI;
            #pragma unroll
            for (int p = 0; p < 16; ++p) {
                float ml = mu_s[o * 17 + p];
                float isg = isig_s[o * 17 + p];
                cst -= 0.5f * lsig_s[o * 17 + p];
                float d0 = v[0][p] - ml; s0 = fmaf(d0 * d0, isg, s0);
                float d1 = v[1][p] - ml; s1 = fmaf(d1 * d1, isg, s1);
                float d2 = v[2][p] - ml; s2 = fmaf(d2 * d2, isg, s2);
                float d3 = v[3][p] - ml; s3 = fmaf(d3 * d3, isg, s3);
            }
            const float la = laout_s[o];
            rws[(g      ) * 11 + o] = fmaf(-0.5f, s0, cst) + la;
            rws[(g +  64) * 11 + o] = fmaf(-0.5f, s1, cst) + la;
            rws[(g + 128) * 11 + o] = fmaf(-0.5f, s2, cst) + la;
            rws[(g + 192) * 11 + o] = fmaf(-0.5f, s3, cst) + la;
        }
        __syncthreads();
    }
    if (t < 10) atomicAdd(&out[bidx * 10 + t], aout_s[t] * 0.04f);
}

extern "C" void kernel_launch(void* const* d_in, const int* in_sizes, int n_in,
                              void* d_out, int out_size, void* d_ws, size_t ws_size,
                              hipStream_t stream)
{
    const float* x           = (const float*)d_in[0];
    const float* conv_a_w    = (const float*)d_in[1];
    const float* conv_pose_w = (const float*)d_in[2];
    const float* bn_a_g = (const float*)d_in[3];
    const float* bn_a_b = (const float*)d_in[4];
    const float* bn_a_m = (const float*)d_in[5];
    const float* bn_a_v = (const float*)d_in[6];
    const float* bn_p_g = (const float*)d_in[7];
    const float* bn_p_b = (const float*)d_in[8];
    const float* bn_p_m = (const float*)d_in[9];
    const float* bn_p_v = (const float*)d_in[10];
    const float* em0_W  = (const float*)d_in[11];
    const float* em0_bu = (const float*)d_in[12];
    const float* em0_ba = (const float*)d_in[13];
    const float* bn0_g  = (const float*)d_in[14];
    const float* bn0_b  = (const float*)d_in[15];
    const float* bn0_m  = (const float*)d_in[16];
    const float* bn0_v  = (const float*)d_in[17];
    const float* em1_W  = (const float*)d_in[18];
    const float* em1_bu = (const float*)d_in[19];
    const float* em1_ba = (const float*)d_in[20];
    const float* bn1_g  = (const float*)d_in[21];
    const float* bn1_b  = (const float*)d_in[22];
    const float* bn1_m  = (const float*)d_in[23];
    const float* bn1_v  = (const float*)d_in[24];
    const float* fc_W   = (const float*)d_in[25];
    const float* fc_bu  = (const float*)d_in[26];
    const float* fc_ba  = (const float*)d_in[27];

    float* ws    = (float*)d_ws;
    float* a0    = ws;
    float* pose0 = a0 + 32768;
    float* a1    = pose0 + 524288;
    float* pose1 = a1 + 32768;
    float* a2    = pose1 + 524288;
    float* pose2 = a2 + 32768;
    float* out   = (float*)d_out;

    hipMemsetAsync(d_out, 0, (size_t)out_size * sizeof(float), stream);
    hipMemsetAsync(a0, 0, (size_t)(32768 + 524288) * sizeof(float), stream);
    // conv_a: OC=16, NACC=4 (16 oc/block), nOcg=1, nIcq=8, icChunk=32 -> 256 blocks
    k_conv3<4><<<256, 256, 0, stream>>>(x, conv_a_w, bn_a_g, bn_a_b, bn_a_m, bn_a_v,
                                        a0, 16, 1, 8, 32);
    // conv_pose: OC=256, NACC=8 (32 oc/block), nOcg=8, nIcq=8, icChunk=32 -> 2048 blocks
    k_conv3<8><<<2048, 256, 0, stream>>>(x, conv_pose_w, bn_p_g, bn_p_b, bn_p_m, bn_p_v,
                                         pose0, 256, 8, 8, 32);
    k_sig<<<128, 256, 0, stream>>>(a0, 32768);
    k_em_conv<<<2048, 768, 0, stream>>>(a0, pose0, em0_W, em0_bu, em0_ba,
                                        bn0_g, bn0_b, bn0_m, bn0_v, a1, pose1);
    k_em_conv<<<2048, 768, 0, stream>>>(a1, pose1, em1_W, em1_bu, em1_ba,
                                        bn1_g, bn1_b, bn1_m, bn1_v, a2, pose2);
    k_em_fc<<<800, 640, 0, stream>>>(a2, pose2, fc_W, fc_bu, fc_ba, out);
}